// Round 5
// baseline (901.200 us; speedup 1.0000x reference)
//
#include <hip/hip_runtime.h>

// TinyLSTM: I=128, H=64, C=10, B=256, T=1024
// R12. Post-mortem law (R8-R11): a single wave pays ~19.4 cyc per 16x16x32
// MFMA (845 FLOP/cyc/SIMD -- the ~5cyc number is per-CU!). So R10/R11
// regressed by putting 24 MFMAs in the recurrence wave (~466 cyc of issue on
// the serial path); R9 won only because x-MFMAs ran on other SIMD slots.
// R12: (a) xproj precomputed by a separate GEMM dispatch into a 256MB f32
// workspace P[b][t][i*64+u] (same pack/MFMA order as R9 -> bit-identical);
// (b) recurrence keeps ONLY the 8 h-MFMAs (155 SIMD-cyc, mostly in the
// hb-read shadow); (c) 8 batches share the MFMA N dim (2x replication, was
// 4x): same 8 MFMAs serve 8 batches -> 32 blocks; extraction shallower
// (1 cndmask), act = 2 units/lane (parallel chains), h-write still one
// ds_write_b32 (pack2 of adjacent units). Seeds stream from P via a depth-2
// vm-pipe register ring (issued 2 steps = ~1000 cyc ahead; lgkm-only
// barriers never drain them). LDS = H2 only (2.3 KB).
// Fallback (ws < 256MB): in-wave x-MFMA from a f32 x ring (correct, slow).

#define NI 128
#define NH 64
#define NB 256
#define NT 1024
#define NC 10
#define NBB 8               // batches per rec block
#define NBLK (NB / NBB)     // 32 rec blocks

#define LOG2E    1.44269504f
#define TWOLOG2E 2.88539008f

typedef __fp16 half2v __attribute__((ext_vector_type(2)));
typedef __fp16 f16x8  __attribute__((ext_vector_type(8)));
typedef float  f32x4  __attribute__((ext_vector_type(4)));

#define HP2 72   // H2 row stride (halves): 144 B, 16B-aligned, <=2-way banks

#define MF(acc, a, b) \
    acc = __builtin_amdgcn_mfma_f32_16x16x32_f16(a, b, acc, 0, 0, 0)

__device__ __forceinline__ void block_sync_lds() {
    asm volatile("s_waitcnt lgkmcnt(0)\n\ts_barrier" ::: "memory");
}
__device__ __forceinline__ float fast_exp2(float x) {
#if __has_builtin(__builtin_amdgcn_exp2f)
    return __builtin_amdgcn_exp2f(x);
#else
    return __exp2f(x);
#endif
}
__device__ __forceinline__ float fast_rcp(float x) {
    return __builtin_amdgcn_rcpf(x);
}
__device__ __forceinline__ unsigned pack2(float a, float b) {
    half2v h = __builtin_amdgcn_cvt_pkrtz(a, b);
    return __builtin_bit_cast(unsigned, h);
}
__device__ __forceinline__ f16x8 pack8(float4 a, float4 b, float s) {
    half2v p0 = __builtin_amdgcn_cvt_pkrtz(a.x * s, a.y * s);
    half2v p1 = __builtin_amdgcn_cvt_pkrtz(a.z * s, a.w * s);
    half2v p2 = __builtin_amdgcn_cvt_pkrtz(b.x * s, b.y * s);
    half2v p3 = __builtin_amdgcn_cvt_pkrtz(b.z * s, b.w * s);
    f16x8 r;
    r[0]=p0[0]; r[1]=p0[1]; r[2]=p1[0]; r[3]=p1[1];
    r[4]=p2[0]; r[5]=p2[1]; r[6]=p3[0]; r[7]=p3[1];
    return r;
}
__device__ __forceinline__ f16x8 pack8n(float4 a, float4 b) {
    half2v p0 = __builtin_amdgcn_cvt_pkrtz(a.x, a.y);
    half2v p1 = __builtin_amdgcn_cvt_pkrtz(a.z, a.w);
    half2v p2 = __builtin_amdgcn_cvt_pkrtz(b.x, b.y);
    half2v p3 = __builtin_amdgcn_cvt_pkrtz(b.z, b.w);
    f16x8 r;
    r[0]=p0[0]; r[1]=p0[1]; r[2]=p1[0]; r[3]=p1[1];
    r[4]=p2[0]; r[5]=p2[1]; r[6]=p3[0]; r[7]=p3[1];
    return r;
}

// ---- kernel A: P[b][t][i*64+u] = s_i*(W_ih@x + b_ih + b_hh), f32 ----
// Same frag layout / pack path / MFMA accumulation order as the R9 producer
// -> bit-identical seeds. 256 blocks (one batch each), MFMA/HBM-overlapped.
__global__ __launch_bounds__(256, 1)
void xproj_gemm(const float* __restrict__ x, const float* __restrict__ W_ih,
                const float* __restrict__ b_ih, const float* __restrict__ b_hh,
                float* __restrict__ P) {
    const int tid = threadIdx.x, w = tid >> 6, lane = tid & 63;
    const int col = lane & 15, quad = lane >> 4;
    const int b = blockIdx.x;

    f16x8 afrX[4][4];
    f32x4 biasf[4];
    #pragma unroll
    for (int i = 0; i < 4; ++i) {
        const int grow = 64 * i + 16 * w + col;
        const float s = (i == 2) ? TWOLOG2E : LOG2E;
        const float* Wx = W_ih + (size_t)grow * NI;
        #pragma unroll
        for (int ks = 0; ks < 4; ++ks) {
            float4 a4 = *(const float4*)(Wx + ks * 32 + quad * 8);
            float4 b4 = *(const float4*)(Wx + ks * 32 + quad * 8 + 4);
            afrX[i][ks] = pack8(a4, b4, s);
        }
        #pragma unroll
        for (int r = 0; r < 4; ++r) {
            const int u = 64 * i + 16 * w + 4 * quad + r;
            biasf[i][r] = (b_ih[u] + b_hh[u]) * s;
        }
    }

    for (int it = 0; it < NT / 16; ++it) {
        const int t = it * 16 + col;               // N = 16 timesteps
        const float* xp = x + ((size_t)b * NT + t) * NI + quad * 8;
        f16x8 xb[4];
        #pragma unroll
        for (int ks = 0; ks < 4; ++ks) {
            float4 p0 = *(const float4*)(xp + ks * 32);
            float4 p1 = *(const float4*)(xp + ks * 32 + 4);
            xb[ks] = pack8n(p0, p1);
        }
        f32x4 c0 = biasf[0], c1 = biasf[1], c2 = biasf[2], c3 = biasf[3];
        #pragma unroll
        for (int ks = 0; ks < 4; ++ks) {
            MF(c0, afrX[0][ks], xb[ks]);
            MF(c1, afrX[1][ks], xb[ks]);
            MF(c2, afrX[2][ks], xb[ks]);
            MF(c3, afrX[3][ks], xb[ks]);
        }
        // lane's C rows r are units 16w+4quad+r of gate block i -> [i][u]
        float* wp = P + ((size_t)b * NT + t) * 256 + 16 * w + 4 * quad;
        *(f32x4*)(wp)       = c0;
        *(f32x4*)(wp + 64)  = c1;
        *(f32x4*)(wp + 128) = c2;
        *(f32x4*)(wp + 192) = c3;
    }
}

// ---- kernel B: recurrence, 8 batches in N (2x replication) ----
template<int PRE>
__global__ __launch_bounds__(256, 1)
void lstm_rec8(const float* __restrict__ x, const float* __restrict__ P,
               const float* __restrict__ W_ih, const float* __restrict__ W_hh,
               const float* __restrict__ b_ih, const float* __restrict__ b_hh,
               const float* __restrict__ W_cls, const float* __restrict__ b_cls,
               float* __restrict__ out) {
    const int tid = threadIdx.x, w = tid >> 6, lane = tid & 63;
    const int col = lane & 15, quad = lane >> 4;
    const int bb = blockIdx.x;          // batches [8bb, 8bb+8)
    const int bcol = col & 7;           // batch within group
    const int cr   = col >> 3;          // unit-pair select (2 units/lane)

    __shared__ __align__(16) __fp16 H2[2][NBB][HP2];   // 2.3 KB

    f16x8 afrH[4][2];
    #pragma unroll
    for (int i = 0; i < 4; ++i) {
        const int grow = 64 * i + 16 * w + col;
        const float s = (i == 2) ? TWOLOG2E : LOG2E;
        const float* Wh = W_hh + (size_t)grow * NH;
        #pragma unroll
        for (int ks = 0; ks < 2; ++ks) {
            float4 a4 = *(const float4*)(Wh + ks * 32 + quad * 8);
            float4 b4 = *(const float4*)(Wh + ks * 32 + quad * 8 + 4);
            afrH[i][ks] = pack8(a4, b4, s);
        }
    }

    f16x8 afrX[4][4];
    f32x4 biasf[4];
    if constexpr (!PRE) {
        #pragma unroll
        for (int i = 0; i < 4; ++i) {
            const int grow = 64 * i + 16 * w + col;
            const float s = (i == 2) ? TWOLOG2E : LOG2E;
            const float* Wx = W_ih + (size_t)grow * NI;
            #pragma unroll
            for (int ks = 0; ks < 4; ++ks) {
                float4 a4 = *(const float4*)(Wx + ks * 32 + quad * 8);
                float4 b4 = *(const float4*)(Wx + ks * 32 + quad * 8 + 4);
                afrX[i][ks] = pack8(a4, b4, s);
            }
            #pragma unroll
            for (int r = 0; r < 4; ++r) {
                const int u = 64 * i + 16 * w + 4 * quad + r;
                biasf[i][r] = (b_ih[u] + b_hh[u]) * s;
            }
        }
    }

    for (int z = tid; z < 2 * NBB * HP2 / 2; z += 256)
        ((unsigned*)H2)[z] = 0u;        // zero both H bufs

    // seed / x streams (vm pipe, depth-2 register ring, 2 steps ahead)
    const float* Pb  = P + ((size_t)(NBB * bb + bcol) * NT) * 256
                         + 16 * w + 4 * quad;
    const float* xb8 = x + ((size_t)(NBB * bb + bcol) * NT) * NI + quad * 8;
    f32x4 sA[4], sB[4];
    f32x4 xrA[4][2], xrB[4][2];
    auto load_seed = [&](f32x4 (&s)[4], int t) {
        const float* rp = Pb + (size_t)t * 256;
        s[0] = *(const f32x4*)(rp);
        s[1] = *(const f32x4*)(rp + 64);
        s[2] = *(const f32x4*)(rp + 128);
        s[3] = *(const f32x4*)(rp + 192);
    };
    auto load_x = [&](f32x4 (&xr)[4][2], int t) {
        const float* rp = xb8 + (size_t)t * NI;
        #pragma unroll
        for (int ks = 0; ks < 4; ++ks) {
            xr[ks][0] = *(const f32x4*)(rp + ks * 32);
            xr[ks][1] = *(const f32x4*)(rp + ks * 32 + 4);
        }
    };
    if constexpr (PRE) { load_seed(sA, 0); load_seed(sB, 1); }
    else               { load_x(xrA, 0);  load_x(xrB, 1);  }

    block_sync_lds();       // publish H2 zeros

    float cc0 = 0.f, cc1 = 0.f;     // cell state for the lane's 2 units

    auto step = [&](f32x4 (&sd)[4], f32x4 (&xr)[4][2], int t, int cur) {
        // 1) h B-frags (B[k][n]=h[k][bcol], 2x broadcast): the shadow
        const __fp16* Hc = &H2[cur][bcol][quad * 8];
        f16x8 hb0 = *(const f16x8*)(Hc);
        f16x8 hb1 = *(const f16x8*)(Hc + 32);
        // 2) accumulators: precomputed seed (PRE) or bias + in-wave x-MFMA
        f32x4 a0, a1, a2, a3;
        if constexpr (PRE) {
            a0 = sd[0]; a1 = sd[1]; a2 = sd[2]; a3 = sd[3];
        } else {
            a0 = biasf[0]; a1 = biasf[1]; a2 = biasf[2]; a3 = biasf[3];
            #pragma unroll
            for (int ks = 0; ks < 4; ++ks) {
                f16x8 xbv = pack8n((float4&)xr[ks][0], (float4&)xr[ks][1]);
                MF(a2, afrX[2][ks], xbv); MF(a0, afrX[0][ks], xbv);
                MF(a1, afrX[1][ks], xbv); MF(a3, afrX[3][ks], xbv);
            }
        }
        // 3) the 8 irreducible h-MFMAs; g-gate (a2) first
        MF(a2, afrH[2][0], hb0); MF(a0, afrH[0][0], hb0);
        MF(a1, afrH[1][0], hb0); MF(a3, afrH[3][0], hb0);
        MF(a2, afrH[2][1], hb1); MF(a0, afrH[0][1], hb1);
        MF(a1, afrH[1][1], hb1); MF(a3, afrH[3][1], hb1);
        // 4) refill ring for t+2 (vm pipe, off the lgkm critical path)
        if (t + 2 < NT) {
            if constexpr (PRE) load_seed(sd, t + 2);
            else               load_x(xr, t + 2);
        }
        // 5) extract this lane's 2 units (rows 2cr, 2cr+1): 1 cndmask each
        float g0 = cr ? a2[2] : a2[0], g1 = cr ? a2[3] : a2[1];
        float i0 = cr ? a0[2] : a0[0], i1 = cr ? a0[3] : a0[1];
        float f0 = cr ? a1[2] : a1[0], f1 = cr ? a1[3] : a1[1];
        float o0 = cr ? a3[2] : a3[0], o1 = cr ? a3[3] : a3[1];
        // 6) activations (two independent chains, paired rcps)
        float Eg0 = fast_exp2(fminf(g0, 60.f)), Eg1 = fast_exp2(fminf(g1, 60.f));
        float Ei0 = fast_exp2(-i0), Ei1 = fast_exp2(-i1);
        float Ef0 = fast_exp2(-f0), Ef1 = fast_exp2(-f1);
        float Eo0 = fast_exp2(-o0), Eo1 = fast_exp2(-o1);
        float ig0 = (Eg0 - 1.f) * fast_rcp((1.f + Ei0) * (1.f + Eg0));
        float ig1 = (Eg1 - 1.f) * fast_rcp((1.f + Ei1) * (1.f + Eg1));
        float fv0 = fast_rcp(1.f + Ef0), fv1 = fast_rcp(1.f + Ef1);
        cc0 = fmaf(fv0, cc0, ig0);
        cc1 = fmaf(fv1, cc1, ig1);
        float Ec0 = fast_exp2(fminf(TWOLOG2E * cc0, 60.f));
        float Ec1 = fast_exp2(fminf(TWOLOG2E * cc1, 60.f));
        float h0 = (Ec0 - 1.f) * fast_rcp((1.f + Eo0) * (1.f + Ec0));
        float h1 = (Ec1 - 1.f) * fast_rcp((1.f + Eo1) * (1.f + Ec1));
        // 7) adjacent unit pair -> one ds_write_b32
        *(unsigned*)((char*)&H2[cur ^ 1][bcol][0]
                     + (16 * w + 4 * quad + 2 * cr) * 2) = pack2(h0, h1);
        block_sync_lds();
    };

    for (int k = 0; k < NT / 2; ++k) {
        step(sA, xrA, 2 * k, 0);
        step(sB, xrB, 2 * k + 1, 1);
    }
    // t=1023 (cur=1) wrote H2[0] = h_T; its barrier already executed.

    if (tid < NBB * NC) {
        const int bl = tid / NC, cl = tid % NC;
        float acc = b_cls[cl];
        const float* wc = W_cls + cl * NH;
        #pragma unroll 8
        for (int kk = 0; kk < NH; ++kk)
            acc = fmaf(wc[kk], (float)H2[0][bl][kk], acc);
        out[(NBB * bb + bl) * NC + cl] = acc;
    }
}

extern "C" void kernel_launch(void* const* d_in, const int* in_sizes, int n_in,
                              void* d_out, int out_size, void* d_ws, size_t ws_size,
                              hipStream_t stream) {
    const float* x     = (const float*)d_in[0];
    const float* W_ih  = (const float*)d_in[1];
    const float* W_hh  = (const float*)d_in[2];
    const float* b_ih  = (const float*)d_in[3];
    const float* b_hh  = (const float*)d_in[4];
    const float* W_cls = (const float*)d_in[5];
    const float* b_cls = (const float*)d_in[6];
    float* out = (float*)d_out;

    const size_t need = (size_t)NB * NT * 256 * sizeof(float);   // 256 MiB
    if (d_ws != nullptr && ws_size >= need) {
        float* P = (float*)d_ws;
        xproj_gemm<<<NB, 256, 0, stream>>>(x, W_ih, b_ih, b_hh, P);
        lstm_rec8<1><<<NBLK, 256, 0, stream>>>(x, P, W_ih, W_hh, b_ih, b_hh,
                                               W_cls, b_cls, out);
    } else {
        lstm_rec8<0><<<NBLK, 256, 0, stream>>>(x, nullptr, W_ih, W_hh, b_ih,
                                               b_hh, W_cls, b_cls, out);
    }
}

// Round 7
// 496.753 us; speedup vs baseline: 1.8142x; 1.8142x over previous
//
#include <hip/hip_runtime.h>

// TinyLSTM: I=128, H=64, C=10, B=256, T=1024
// R13 = R9 (best: 306us) + non-draining barriers + smoothed producer slots.
// Post-mortem law (R10/R11/R12 triangulation): an asm barrier with a
// "memory" clobber forces a FULL vmcnt drain every step -> any global
// prefetch (reg ring or global_load_lds) has zero effective lead and puts
// ~400-900 cyc of HBM/L3 latency on the serial recurrence path. That (a)
// explains R10..R12's regressions, (b) leaves ~170 cyc of producer straggle
// inside R9 (producers force-drained their slot-1 glls at the slot-1
// barrier). Fix:
//  - barriers are now clobberless "s_waitcnt lgkmcnt(0)" + raw s_barrier
//    (HK/m218 pattern: loads stay in flight ACROSS barriers);
//  - producers drain vmcnt once at slot 3, ~2 slots (~1100 cyc) after the
//    slot-1 issue -> ~0 stall;
//  - the 16-MFMA produce burst is split across slots 0 and 2 (ksteps 0-1,
//    then 2-3 + P-write; same accumulation order -> bit-identical), so no
//    producer slot exceeds ~320 cyc and the workgroup barrier never waits
//    on a producer.
// Consumers (waves 0-3) are vm-free in the loop and keep R9's exact minimal
// body: 2 hb ds_reads -> 8 h-MFMAs -> seed prefetch -> activation ->
// 1 ds_write -> lgkm-only barrier. Sync ledger == R9 (every cross-wave edge
// separated by >=1 barrier). LDS: XS 16K + P 34.3K + H2 1.3K = 52K.
// (Round 6 bench was a GPUAcquisitionTimeout -- R13 never measured;
// resubmitted unchanged.)

#define NI 128
#define NH 64
#define NB 256
#define NT 1024
#define NC 10

#define TT 4
#define NTILE (NT / TT)

#define LOG2E    1.44269504f
#define TWOLOG2E 2.88539008f

typedef __fp16 half2v __attribute__((ext_vector_type(2)));
typedef __fp16 f16x8  __attribute__((ext_vector_type(8)));
typedef float  f32x4  __attribute__((ext_vector_type(4)));

#define HP  80           // H row stride (halves): 160 B, max 2-way banks
#define XPB 268          // xproj batch stride (floats)
#define XPT (4 * XPB)    // xproj timestep stride (floats)

#define MF(acc, a, b) \
    acc = __builtin_amdgcn_mfma_f32_16x16x32_f16(a, b, acc, 0, 0, 0)

// Non-draining publish barrier: waits ONLY lgkm (LDS writes visible), never
// vmcnt -- in-flight global loads survive. No "memory" clobber: the volatile
// asm is still a scheduling barrier for memory ops (chain deps in the MI
// scheduler), and s_barrier is convergent+side-effecting, so LDS ops don't
// cross at IR level either.
__device__ __forceinline__ void block_sync_lds() {
    asm volatile("s_waitcnt lgkmcnt(0)");
    __builtin_amdgcn_s_barrier();
}
__device__ __forceinline__ void wave_drain_vm() {
    asm volatile("s_waitcnt vmcnt(0)");
}
__device__ __forceinline__ float fast_exp2(float x) {
#if __has_builtin(__builtin_amdgcn_exp2f)
    return __builtin_amdgcn_exp2f(x);
#else
    return __exp2f(x);
#endif
}
__device__ __forceinline__ float fast_rcp(float x) {
    return __builtin_amdgcn_rcpf(x);
}
__device__ __forceinline__ f16x8 pack8(float4 a, float4 b, float s) {
    half2v p0 = __builtin_amdgcn_cvt_pkrtz(a.x * s, a.y * s);
    half2v p1 = __builtin_amdgcn_cvt_pkrtz(a.z * s, a.w * s);
    half2v p2 = __builtin_amdgcn_cvt_pkrtz(b.x * s, b.y * s);
    half2v p3 = __builtin_amdgcn_cvt_pkrtz(b.z * s, b.w * s);
    f16x8 r;
    r[0]=p0[0]; r[1]=p0[1]; r[2]=p1[0]; r[3]=p1[1];
    r[4]=p2[0]; r[5]=p2[1]; r[6]=p3[0]; r[7]=p3[1];
    return r;
}
__device__ __forceinline__ f16x8 pack8n(float4 a, float4 b) {
    half2v p0 = __builtin_amdgcn_cvt_pkrtz(a.x, a.y);
    half2v p1 = __builtin_amdgcn_cvt_pkrtz(a.z, a.w);
    half2v p2 = __builtin_amdgcn_cvt_pkrtz(b.x, b.y);
    half2v p3 = __builtin_amdgcn_cvt_pkrtz(b.z, b.w);
    f16x8 r;
    r[0]=p0[0]; r[1]=p0[1]; r[2]=p1[0]; r[3]=p1[1];
    r[4]=p2[0]; r[5]=p2[1]; r[6]=p3[0]; r[7]=p3[1];
    return r;
}
__device__ __forceinline__ void gload_lds16(const void* g, void* l) {
    __builtin_amdgcn_global_load_lds(
        (const __attribute__((address_space(1))) unsigned int*)g,
        (__attribute__((address_space(3))) unsigned int*)l, 16, 0, 0);
}

__global__ __launch_bounds__(512, 2)
void lstm_one(const float* __restrict__ x,
              const float* __restrict__ W_ih,
              const float* __restrict__ W_hh,
              const float* __restrict__ b_ih,
              const float* __restrict__ b_hh,
              const float* __restrict__ W_cls,
              const float* __restrict__ b_cls,
              float* __restrict__ out) {
    const int tid  = threadIdx.x;
    const int w4   = tid >> 6;          // 0..7
    const bool cons = (w4 < 4);         // waves 0-3: recurrence consumers
    const int w    = w4 & 3;            // role-local wave id
    const int lane = tid & 63;
    const int col  = lane & 15;         // MFMA n-column
    const int quad = lane >> 4;
    const int bb   = blockIdx.x;        // batches [4bb, 4bb+4)
    const int bcol = col & 3;           // batch within group
    const int cr   = col >> 2;

    __shared__ __align__(16) float  XS[2][4][TT * NI];  // raw x, dbl-buf 16K
    __shared__ __align__(16) float  P[2][TT * XPT];     // xproj f32, dbl 34.3K
    __shared__ __align__(16) __fp16 H2[2][4][HP];       // h f16, dbl-buf 1.3K

    if (!cons) {
        // ================= PRODUCER (waves 4-7) =================
        // stage batch (4bb+w), tile -> XS[tile&1][w]. LDS dest linear; src
        // addr ^xo, xo=((row^(row>>1))&7)<<4, row=(w*2048+lin)>>9.
        // Involutive, within-128B-line: coalescing unchanged, 2-way LDS.
        auto stage_x = [&](int tile) {
            const char* xsrc = (const char*)(x + ((size_t)(4 * bb + w) * NT
                                                  + (size_t)tile * TT) * NI);
            #pragma unroll
            for (int j = 0; j < 2; ++j) {
                const unsigned lin = j * 1024u + (unsigned)lane * 16u;
                const unsigned row = ((unsigned)w * 2048u + lin) >> 9;
                const unsigned xo  = ((row ^ (row >> 1)) & 7u) << 4;
                gload_lds16(xsrc + (lin ^ xo),
                            (char*)&XS[tile & 1][w][0] + j * 1024);
            }
        };
        stage_x(0);
        stage_x(1);

        // W_ih A-frags + prescaled bias (producer only)
        f16x8 afrX[4][4];
        f32x4 biasf[4];
        #pragma unroll
        for (int i = 0; i < 4; ++i) {
            const int grow = 64 * i + 16 * w + col;
            const float s = (i == 2) ? TWOLOG2E : LOG2E;
            const float* Wx = W_ih + (size_t)grow * NI;
            #pragma unroll
            for (int ks = 0; ks < 4; ++ks) {
                float4 a4 = *(const float4*)(Wx + ks * 32 + quad * 8);
                float4 b4 = *(const float4*)(Wx + ks * 32 + quad * 8 + 4);
                afrX[i][ks] = pack8(a4, b4, s);
            }
            #pragma unroll
            for (int r = 0; r < 4; ++r) {
                const int u = 64 * i + 16 * w + 4 * quad + r;
                biasf[i][r] = (b_ih[u] + b_hh[u]) * s;
            }
        }

        // per-lane produce addressing (timestep tl = cr, batch bcol)
        const unsigned rowP = (unsigned)(bcol * 4 + cr);
        const unsigned xoP  = ((rowP ^ (rowP >> 1)) & 7u) << 4;
        const unsigned rbP  = rowP * 512u + (unsigned)quad * 32u;

        // produce tile tp's xproj in two halves (ksteps 0-1, then 2-3 +
        // P-write). Same MFMA accumulation order as one burst ->
        // bit-identical. pc* persist across the intervening barriers.
        f32x4 pc0, pc1, pc2, pc3;
        auto produce_half = [&](int tp, int h) {
            const char* XSb = (const char*)&XS[tp & 1][0][0];
            if (h == 0) {
                pc0 = biasf[0]; pc1 = biasf[1];
                pc2 = biasf[2]; pc3 = biasf[3];
            }
            #pragma unroll
            for (int kk = 0; kk < 2; ++kk) {
                const int ks = 2 * h + kk;
                const unsigned l0 = rbP + (unsigned)ks * 128u;
                float4 p0 = *(const float4*)(XSb + (l0 ^ xoP));
                float4 p1 = *(const float4*)(XSb + ((l0 + 16u) ^ xoP));
                f16x8 xbv = pack8n(p0, p1);
                MF(pc0, afrX[0][ks], xbv);
                MF(pc1, afrX[1][ks], xbv);
                MF(pc2, afrX[2][ks], xbv);
                MF(pc3, afrX[3][ks], xbv);
            }
            if (h == 1) {
                float* wp = &P[tp & 1][0] + cr * XPT + bcol * XPB
                            + 16 * w + 4 * quad;
                *(f32x4*)(wp)       = pc0;
                *(f32x4*)(wp + 64)  = pc1;
                *(f32x4*)(wp + 128) = pc2;
                *(f32x4*)(wp + 192) = pc3;
            }
        };

        wave_drain_vm();        // x_0, x_1 landed (own)
        block_sync_lds();       // [A] all producers' stages visible
        produce_half(0, 0);     // P[0] <- xproj tile 0 (full, prologue)
        produce_half(0, 1);
        block_sync_lds();       // [B] P[0] visible to consumers

        for (int k = 0; k < NTILE; ++k) {
            const int doP = (k + 1 < NTILE);
            // slot 0: first half of tile k+1's xproj (reads XS[(k+1)&1],
            // published at tile k-1 slot 3)
            if (doP) produce_half(k + 1, 0);
            block_sync_lds();
            // slot 1: stage x_{k+2} -> XS[k&1] (that buffer's last reads
            // finished at tile k-1 slot 2; glls stay in flight -- the
            // clobberless barrier no longer drains them)
            if (k + 2 < NTILE) stage_x(k + 2);
            block_sync_lds();
            // slot 2: second half + P-write (consumers' last read of
            // P[(k+1)&1] was at tile k-1, >=2 barriers ago)
            if (doP) produce_half(k + 1, 1);
            block_sync_lds();
            // slot 3: drain own glls (~2 slots = ~1100 cyc old -> ~free);
            // the following barrier publishes them for tile k+1's reads
            wave_drain_vm();
            block_sync_lds();
        }
        return;   // barrier counts matched with consumers
    }

    // ================= CONSUMER (waves 0-3) =================
    __builtin_amdgcn_s_setprio(1);      // recurrence chain is the wall time

    // W_hh A-frags (consumer only; seed comes from P)
    f16x8 afrH[4][2];
    #pragma unroll
    for (int i = 0; i < 4; ++i) {
        const int grow = 64 * i + 16 * w + col;
        const float s = (i == 2) ? TWOLOG2E : LOG2E;
        const float* Wh = W_hh + (size_t)grow * NH;
        #pragma unroll
        for (int ks = 0; ks < 2; ++ks) {
            float4 a4 = *(const float4*)(Wh + ks * 32 + quad * 8);
            float4 b4 = *(const float4*)(Wh + ks * 32 + quad * 8 + 4);
            afrH[i][ks] = pack8(a4, b4, s);
        }
    }
    for (int z = tid; z < 2 * 4 * HP / 2; z += 256)
        ((unsigned*)H2)[z] = 0u;        // zero both H bufs

    block_sync_lds();       // [A] (match producer)
    block_sync_lds();       // [B] P[0] ready

    float c = 0.f;
    f32x4 xa0, xa1, xa2, xa3;           // xproj seed, prefetched (static regs)
    auto load_xa = [&](const float* Pb, int tt) {
        const float* rp = Pb + tt * XPT + bcol * XPB + 16 * w + 4 * quad;
        xa0 = *(const f32x4*)(rp);
        xa1 = *(const f32x4*)(rp + 64);
        xa2 = *(const f32x4*)(rp + 128);
        xa3 = *(const f32x4*)(rp + 192);
    };
    load_xa(&P[0][0], 0);

    for (int k = 0; k < NTILE; ++k) {
        #pragma unroll
        for (int tt = 0; tt < TT; ++tt) {
            const int cur = tt & 1;     // s=4k+tt -> parity = tt&1
            const __fp16* Hc = &H2[cur][bcol][quad * 8];
            f16x8 hb0 = *(const f16x8*)(Hc);
            f16x8 hb1 = *(const f16x8*)(Hc + 32);
            f32x4 a0 = xa0, a1 = xa1, a2 = xa2, a3 = xa3;
            MF(a2, afrH[2][0], hb0);    // g first: longest act chain
            MF(a0, afrH[0][0], hb0);
            MF(a1, afrH[1][0], hb0);
            MF(a2, afrH[2][1], hb1);
            MF(a0, afrH[0][1], hb1);
            MF(a1, afrH[1][1], hb1);
            MF(a3, afrH[3][0], hb0);    // o last: needed at the very end
            MF(a3, afrH[3][1], hb1);
            // prefetch next seed (off critical path; drains at step barrier)
            if (tt < TT - 1)           load_xa(&P[k & 1][0], tt + 1);
            else if (k + 1 < NTILE)    load_xa(&P[(k + 1) & 1][0], 0);
            // activation: one unit (u=16w+4quad+cr, batch bcol); paired rcps
            float Eg = fast_exp2(fminf(a2[cr], 60.f));
            float Ei = fast_exp2(-a0[cr]);
            float Ef = fast_exp2(-a1[cr]);
            float Eo = fast_exp2(-a3[cr]);
            float ig = (Eg - 1.f) * fast_rcp((1.f + Ei) * (1.f + Eg));
            float fv = fast_rcp(1.f + Ef);
            c = fmaf(fv, c, ig);
            float Ec = fast_exp2(fminf(TWOLOG2E * c, 60.f));
            float h  = (Ec - 1.f) * fast_rcp((1.f + Eo) * (1.f + Ec));
            H2[cur ^ 1][bcol][16 * w + 4 * quad + cr] = (__fp16)h;
            block_sync_lds();
        }
    }
    // final h in H2[0] (s=1023: cur=1, writes buf 0); last barrier done.

    if (tid < 4 * NC) {
        const int bl = tid / NC, cl = tid % NC;
        float acc = b_cls[cl];
        const float* wc = W_cls + cl * NH;
        #pragma unroll 8
        for (int kk = 0; kk < NH; ++kk)
            acc = fmaf(wc[kk], (float)H2[0][bl][kk], acc);
        out[(4 * bb + bl) * NC + cl] = acc;
    }
}

extern "C" void kernel_launch(void* const* d_in, const int* in_sizes, int n_in,
                              void* d_out, int out_size, void* d_ws, size_t ws_size,
                              hipStream_t stream) {
    const float* x     = (const float*)d_in[0];
    const float* W_ih  = (const float*)d_in[1];
    const float* W_hh  = (const float*)d_in[2];
    const float* b_ih  = (const float*)d_in[3];
    const float* b_hh  = (const float*)d_in[4];
    const float* W_cls = (const float*)d_in[5];
    const float* b_cls = (const float*)d_in[6];
    float* out = (float*)d_out;

    lstm_one<<<NB / 4, 512, 0, stream>>>(x, W_ih, W_hh, b_ih, b_hh,
                                         W_cls, b_cls, out);
}

// Round 9
// 443.196 us; speedup vs baseline: 2.0334x; 1.1208x over previous
//
#include <hip/hip_runtime.h>

// TinyLSTM: I=128, H=64, C=10, B=256, T=1024
// R14 = exact R9 (best measured: 306us rocprof / 447us bench) + ONE tweak:
// g-gate-first MFMA order in the consumer. Post-mortem history:
//  R8 (1015 cyc/step): xproj bulk on critical path.
//  R9 (719): producer waves + minimal consumer body. BEST.
//  R10 (1153): folding xproj into consumer wave -- 1 wave/SIMD has no
//    co-issue; +19.4 cyc per extra MFMA in the recurrence wave.
//  R11/R12 (1195/1316): global prefetch rings -- the "memory"-clobbered
//    barrier drains vmcnt every step, so prefetch lead is zero and HBM/L3
//    latency lands on the serial path.
//  R13 (844): clobberless barrier + split producer burst REGRESSED: R9's
//    producers never straggled (single 430-cyc burst fits a 719-cyc slot);
//    the split added a second LDS-latency exposure per tile.
// Law: any issue-work or latency exposure added to ANY wave's slot shows up
// ~1:1 in step time. So: revert to R9 byte-for-byte, except the consumer's
// 8 h-MFMAs run a2(g),a0(i),a1(f) first / a3(o) last -- act head needs
// Eg,Ei,Ef, so it starts ~40cyc earlier; o only needed at the end.
// Per-acc accumulation order unchanged (seed->hb0->hb1) -> bit-identical.
// (Rounds 6 and 8 were GPUAcquisitionTimeouts; R14 resubmitted unchanged.)

#define NI 128
#define NH 64
#define NB 256
#define NT 1024
#define NC 10

#define TT 4
#define NTILE (NT / TT)

#define LOG2E    1.44269504f
#define TWOLOG2E 2.88539008f

typedef __fp16 half2v __attribute__((ext_vector_type(2)));
typedef __fp16 f16x8  __attribute__((ext_vector_type(8)));
typedef float  f32x4  __attribute__((ext_vector_type(4)));

#define HP  80           // H row stride (halves): 160 B, max 2-way banks
#define XPB 268          // xproj batch stride (floats)
#define XPT (4 * XPB)    // xproj timestep stride (floats)

#define MF(acc, a, b) \
    acc = __builtin_amdgcn_mfma_f32_16x16x32_f16(a, b, acc, 0, 0, 0)

__device__ __forceinline__ void block_sync_lds() {
    asm volatile("s_waitcnt lgkmcnt(0)\n\ts_barrier" ::: "memory");
}
__device__ __forceinline__ void wave_drain_vm() {
    asm volatile("s_waitcnt vmcnt(0)" ::: "memory");
}
__device__ __forceinline__ float fast_exp2(float x) {
#if __has_builtin(__builtin_amdgcn_exp2f)
    return __builtin_amdgcn_exp2f(x);
#else
    return __exp2f(x);
#endif
}
__device__ __forceinline__ float fast_rcp(float x) {
    return __builtin_amdgcn_rcpf(x);
}
__device__ __forceinline__ f16x8 pack8(float4 a, float4 b, float s) {
    half2v p0 = __builtin_amdgcn_cvt_pkrtz(a.x * s, a.y * s);
    half2v p1 = __builtin_amdgcn_cvt_pkrtz(a.z * s, a.w * s);
    half2v p2 = __builtin_amdgcn_cvt_pkrtz(b.x * s, b.y * s);
    half2v p3 = __builtin_amdgcn_cvt_pkrtz(b.z * s, b.w * s);
    f16x8 r;
    r[0]=p0[0]; r[1]=p0[1]; r[2]=p1[0]; r[3]=p1[1];
    r[4]=p2[0]; r[5]=p2[1]; r[6]=p3[0]; r[7]=p3[1];
    return r;
}
__device__ __forceinline__ f16x8 pack8n(float4 a, float4 b) {
    half2v p0 = __builtin_amdgcn_cvt_pkrtz(a.x, a.y);
    half2v p1 = __builtin_amdgcn_cvt_pkrtz(a.z, a.w);
    half2v p2 = __builtin_amdgcn_cvt_pkrtz(b.x, b.y);
    half2v p3 = __builtin_amdgcn_cvt_pkrtz(b.z, b.w);
    f16x8 r;
    r[0]=p0[0]; r[1]=p0[1]; r[2]=p1[0]; r[3]=p1[1];
    r[4]=p2[0]; r[5]=p2[1]; r[6]=p3[0]; r[7]=p3[1];
    return r;
}
__device__ __forceinline__ void gload_lds16(const void* g, void* l) {
    __builtin_amdgcn_global_load_lds(
        (const __attribute__((address_space(1))) unsigned int*)g,
        (__attribute__((address_space(3))) unsigned int*)l, 16, 0, 0);
}

__global__ __launch_bounds__(512, 2)
void lstm_one(const float* __restrict__ x,
              const float* __restrict__ W_ih,
              const float* __restrict__ W_hh,
              const float* __restrict__ b_ih,
              const float* __restrict__ b_hh,
              const float* __restrict__ W_cls,
              const float* __restrict__ b_cls,
              float* __restrict__ out) {
    const int tid  = threadIdx.x;
    const int w4   = tid >> 6;          // 0..7
    const bool cons = (w4 < 4);         // waves 0-3: recurrence consumers
    const int w    = w4 & 3;            // role-local wave id
    const int lane = tid & 63;
    const int col  = lane & 15;         // MFMA n-column
    const int quad = lane >> 4;
    const int bb   = blockIdx.x;        // batches [4bb, 4bb+4)
    const int bcol = col & 3;           // batch within group
    const int cr   = col >> 2;

    __shared__ __align__(16) float  XS[2][4][TT * NI];  // raw x, dbl-buf 16K
    __shared__ __align__(16) float  P[2][TT * XPT];     // xproj f32, dbl 34.3K
    __shared__ __align__(16) __fp16 H2[2][4][HP];       // h f16, dbl-buf 1.3K

    if (!cons) {
        // ================= PRODUCER (waves 4-7) =================
        // stage batch (4bb+w), tile -> XS[tile&1][w]. LDS dest linear; src
        // addr ^xo, xo=((row^(row>>1))&7)<<4, row=(w*2048+lin)>>9.
        // Involutive, within-128B-line: coalescing unchanged, 2-way LDS.
        auto stage_x = [&](int tile) {
            const char* xsrc = (const char*)(x + ((size_t)(4 * bb + w) * NT
                                                  + (size_t)tile * TT) * NI);
            #pragma unroll
            for (int j = 0; j < 2; ++j) {
                const unsigned lin = j * 1024u + (unsigned)lane * 16u;
                const unsigned row = ((unsigned)w * 2048u + lin) >> 9;
                const unsigned xo  = ((row ^ (row >> 1)) & 7u) << 4;
                gload_lds16(xsrc + (lin ^ xo),
                            (char*)&XS[tile & 1][w][0] + j * 1024);
            }
        };
        stage_x(0);
        stage_x(1);

        // W_ih A-frags + prescaled bias (producer only)
        f16x8 afrX[4][4];
        f32x4 biasf[4];
        #pragma unroll
        for (int i = 0; i < 4; ++i) {
            const int grow = 64 * i + 16 * w + col;
            const float s = (i == 2) ? TWOLOG2E : LOG2E;
            const float* Wx = W_ih + (size_t)grow * NI;
            #pragma unroll
            for (int ks = 0; ks < 4; ++ks) {
                float4 a4 = *(const float4*)(Wx + ks * 32 + quad * 8);
                float4 b4 = *(const float4*)(Wx + ks * 32 + quad * 8 + 4);
                afrX[i][ks] = pack8(a4, b4, s);
            }
            #pragma unroll
            for (int r = 0; r < 4; ++r) {
                const int u = 64 * i + 16 * w + 4 * quad + r;
                biasf[i][r] = (b_ih[u] + b_hh[u]) * s;
            }
        }

        // produce xproj for tile tp: reads XS[tp&1] (all batches -> needs all
        // producers' stages visible: each drained own vmcnt + barrier before)
        auto produce = [&](int tp) {
            const char* XSb = (const char*)&XS[tp & 1][0][0];
            const int tl = cr;                         // timestep 0..3
            const unsigned row = (unsigned)(bcol * 4 + tl);
            const unsigned xo  = ((row ^ (row >> 1)) & 7u) << 4;
            const unsigned rb  = row * 512u + (unsigned)quad * 32u;
            f16x8 xb[4];
            #pragma unroll
            for (int ks = 0; ks < 4; ++ks) {
                const unsigned l0 = rb + ks * 128u;
                float4 p0 = *(const float4*)(XSb + (l0 ^ xo));
                float4 p1 = *(const float4*)(XSb + ((l0 + 16u) ^ xo));
                xb[ks] = pack8n(p0, p1);
            }
            f32x4 c0 = biasf[0], c1 = biasf[1], c2 = biasf[2], c3 = biasf[3];
            #pragma unroll
            for (int ks = 0; ks < 4; ++ks) {
                MF(c0, afrX[0][ks], xb[ks]);
                MF(c1, afrX[1][ks], xb[ks]);
                MF(c2, afrX[2][ks], xb[ks]);
                MF(c3, afrX[3][ks], xb[ks]);
            }
            float* wp = &P[tp & 1][0] + tl * XPT + bcol * XPB
                        + 16 * w + 4 * quad;
            *(f32x4*)(wp)       = c0;
            *(f32x4*)(wp + 64)  = c1;
            *(f32x4*)(wp + 128) = c2;
            *(f32x4*)(wp + 192) = c3;
        };

        wave_drain_vm();        // x_0, x_1 landed (own)
        block_sync_lds();       // [A] all producers' stages visible
        produce(0);             // P[0] <- xproj tile 0
        block_sync_lds();       // [B] P[0] visible to consumers

        for (int k = 0; k < NTILE; ++k) {
            // slot tt=0: next tile's xproj (reads XS[(k+1)&1], writes
            // P[(k+1)&1]; consumers' last read of that P-buffer was at
            // (k-1,tt=2), >=2 barriers ago)
            if (k + 1 < NTILE) produce(k + 1);
            block_sync_lds();
            // slot tt=1: stage x_{k+2} -> XS[k&1] (last ds_reads of that
            // buffer drained at (k-1,tt=0)'s barrier)
            if (k + 2 < NTILE) stage_x(k + 2);
            block_sync_lds();
            // slot tt=2: idle
            block_sync_lds();
            // slot tt=3: drain own staging loads; the following barrier
            // publishes cross-producer completion before tile k+1 reads
            wave_drain_vm();
            block_sync_lds();
        }
        return;   // no epilogue work; barrier counts matched with consumers
    }

    // ================= CONSUMER (waves 0-3) =================
    __builtin_amdgcn_s_setprio(1);      // recurrence chain is the wall time

    // W_hh A-frags (consumer only; no afrX, no bias -- seed comes from P)
    f16x8 afrH[4][2];
    #pragma unroll
    for (int i = 0; i < 4; ++i) {
        const int grow = 64 * i + 16 * w + col;
        const float s = (i == 2) ? TWOLOG2E : LOG2E;
        const float* Wh = W_hh + (size_t)grow * NH;
        #pragma unroll
        for (int ks = 0; ks < 2; ++ks) {
            float4 a4 = *(const float4*)(Wh + ks * 32 + quad * 8);
            float4 b4 = *(const float4*)(Wh + ks * 32 + quad * 8 + 4);
            afrH[i][ks] = pack8(a4, b4, s);
        }
    }
    for (int z = tid; z < 2 * 4 * HP / 2; z += 256)
        ((unsigned*)H2)[z] = 0u;        // zero both H bufs

    block_sync_lds();       // [A] (match producer)
    block_sync_lds();       // [B] P[0] ready

    float c = 0.f;
    f32x4 xa0, xa1, xa2, xa3;           // xproj seed, prefetched (static regs)
    auto load_xa = [&](const float* Pb, int tt) {
        const float* rp = Pb + tt * XPT + bcol * XPB + 16 * w + 4 * quad;
        xa0 = *(const f32x4*)(rp);
        xa1 = *(const f32x4*)(rp + 64);
        xa2 = *(const f32x4*)(rp + 128);
        xa3 = *(const f32x4*)(rp + 192);
    };
    load_xa(&P[0][0], 0);

    for (int k = 0; k < NTILE; ++k) {
        #pragma unroll
        for (int tt = 0; tt < TT; ++tt) {
            const int cur = tt & 1;     // s=4k+tt -> parity = tt&1
            const __fp16* Hc = &H2[cur][bcol][quad * 8];
            f16x8 hb0 = *(const f16x8*)(Hc);
            f16x8 hb1 = *(const f16x8*)(Hc + 32);
            f32x4 a0 = xa0, a1 = xa1, a2 = xa2, a3 = xa3;
            // g(a2),i(a0),f(a1) complete at MFMA 4/5/6 -- act head starts
            // earlier; o(a3) last, only needed at the very end.
            MF(a2, afrH[2][0], hb0);
            MF(a0, afrH[0][0], hb0);
            MF(a1, afrH[1][0], hb0);
            MF(a2, afrH[2][1], hb1);
            MF(a0, afrH[0][1], hb1);
            MF(a1, afrH[1][1], hb1);
            MF(a3, afrH[3][0], hb0);
            MF(a3, afrH[3][1], hb1);
            // prefetch next seed (off critical path; drains at step barrier)
            if (tt < TT - 1)           load_xa(&P[k & 1][0], tt + 1);
            else if (k + 1 < NTILE)    load_xa(&P[(k + 1) & 1][0], 0);
            // activation: one unit (u=16w+4quad+cr, batch bcol); paired rcps
            float Eg = fast_exp2(fminf(a2[cr], 60.f));
            float Ei = fast_exp2(-a0[cr]);
            float Ef = fast_exp2(-a1[cr]);
            float Eo = fast_exp2(-a3[cr]);
            float ig = (Eg - 1.f) * fast_rcp((1.f + Ei) * (1.f + Eg));
            float fv = fast_rcp(1.f + Ef);
            c = fmaf(fv, c, ig);
            float Ec = fast_exp2(fminf(TWOLOG2E * c, 60.f));
            float h  = (Ec - 1.f) * fast_rcp((1.f + Eo) * (1.f + Ec));
            H2[cur ^ 1][bcol][16 * w + 4 * quad + cr] = (__fp16)h;
            block_sync_lds();
        }
    }
    // final h in H2[0] (s=1023: cur=1, writes buf 0); last barrier done.

    if (tid < 4 * NC) {
        const int bl = tid / NC, cl = tid % NC;
        float acc = b_cls[cl];
        const float* wc = W_cls + cl * NH;
        #pragma unroll 8
        for (int kk = 0; kk < NH; ++kk)
            acc = fmaf(wc[kk], (float)H2[0][bl][kk], acc);
        out[(4 * bb + bl) * NC + cl] = acc;
    }
}

extern "C" void kernel_launch(void* const* d_in, const int* in_sizes, int n_in,
                              void* d_out, int out_size, void* d_ws, size_t ws_size,
                              hipStream_t stream) {
    const float* x     = (const float*)d_in[0];
    const float* W_ih  = (const float*)d_in[1];
    const float* W_hh  = (const float*)d_in[2];
    const float* b_ih  = (const float*)d_in[3];
    const float* b_hh  = (const float*)d_in[4];
    const float* W_cls = (const float*)d_in[5];
    const float* b_cls = (const float*)d_in[6];
    float* out = (float*)d_out;

    lstm_one<<<NB / 4, 512, 0, stream>>>(x, W_ih, W_hh, b_ih, b_hh,
                                         W_cls, b_cls, out);
}